// Round 12
// baseline (310.179 us; speedup 1.0000x reference)
//
#include <hip/hip_runtime.h>

typedef short bf16x8 __attribute__((ext_vector_type(8)));
typedef float f32x4 __attribute__((ext_vector_type(4)));
typedef unsigned short u16x4 __attribute__((ext_vector_type(4)));

__device__ __forceinline__ unsigned short f2b(float f) {
    unsigned int u = __builtin_bit_cast(unsigned int, f);
    u += 0x7fffu + ((u >> 16) & 1u);   // RNE
    return (unsigned short)(u >> 16);
}
__device__ __forceinline__ float b2f(unsigned short s) {
    unsigned int u = ((unsigned int)s) << 16;
    return __builtin_bit_cast(float, u);
}

// wt[k][i][j] = bf16(w1[j][k][i]);  k<3, i<128, j<64
__global__ void wt_prepass(const float* __restrict__ w1, unsigned short* __restrict__ wt) {
    int t = blockIdx.x * 256 + threadIdx.x;
    if (t >= 24576) return;
    int j = t & 63;
    int i = (t >> 6) & 127;
    int k = t >> 13;
    wt[t] = f2b(w1[(j * 3 + k) * 128 + i]);
}

// xs: row = a*13 + s; byte = (row<<7) + ((j*2) ^ ((row&7)<<4))   [46592 B]
// t4s (overlay): [ic 0..127][cl 0..7][ll] u16, byte = ic*264 + cl*32 + ll*2   [33792 B]
//   pitch 264 -> bank stride 66 === 2 (mod 32): writes ~2-way, reads ~4-way, no XOR.
// twin TW: owns ll = al;  TW0: a = (al==0)?27:al-1, al<16 ;  TW1: a = 15+al, al<12.

template<int TW>
__device__ __forceinline__ void twin_body(
        const float* __restrict__ xb, float* __restrict__ yb,
        const unsigned short* __restrict__ wt, const float* w0s,
        char* smem, int tid, int bc, int c0) {
    constexpr int NA  = TW ? 12 : 16;
    constexpr int NMT = TW ? 6 : 8;
    constexpr int NLD = TW ? 9 : 12;          // staging iters (CNT/256, exact)
    constexpr int CNT = 64 * NA * 3;

    const int lane = tid & 63;
    const int w    = tid >> 6;
    const int rl   = lane & 15;
    const int jb0  = (lane >> 4) << 3;

    // ---- halo zero-fill (bc0: s=0,11 ; bc3: s=9), twin's a-set only ----
    if ((bc == 0 || bc == 3) && tid < NA * 8) {
        int al = tid >> 3, ch = tid & 7;
        int a  = TW ? (al + 15) : (al ? al - 1 : 27);
        int sl0 = (bc == 0) ? 0 : 9;
        int row = a * 13 + sl0;
        int byte = (row << 7) + ((ch << 4) ^ ((row & 7) << 4));
        *reinterpret_cast<f32x4*>(smem + byte) = f32x4{0.f, 0.f, 0.f, 0.f};
        if (bc == 0) {
            row  = a * 13 + 11;
            byte = (row << 7) + ((ch << 4) ^ ((row & 7) << 4));
            *reinterpret_cast<f32x4*>(smem + byte) = f32x4{0.f, 0.f, 0.f, 0.f};
        }
    }

    int q0, q1, q2;
    if      (bc == 0) { q0 = 0; q1 = 1; q2 = 6; }
    else if (bc == 1) { q0 = 1; q1 = 2; q2 = 3; }
    else if (bc == 2) { q0 = 3; q1 = 4; q2 = 5; }
    else              { q0 = 4; q1 = 5; q2 = 6; }

    // ---- staging: NLD batched loads, then scatter ----
    float4 vbuf[NLD];
#pragma unroll
    for (int u = 0; u < NLD; ++u) {
        int f = tid + (u << 8);               // f < CNT exactly
        int rowi = f / 3, q3 = f - rowi * 3;
        int al, j;
        if (TW) { al = rowi % 12; j = rowi / 12; }
        else    { al = rowi & 15; j = rowi >> 4; }
        int a = TW ? (al + 15) : (al ? al - 1 : 27);
        int q = (q3 == 0) ? q0 : ((q3 == 1) ? q1 : q2);
        vbuf[u] = *reinterpret_cast<const float4*>(xb + (j * 28 + a) * 28 + (q << 2));
    }
#pragma unroll
    for (int u = 0; u < NLD; ++u) {
        int f = tid + (u << 8);
        int rowi = f / 3, q3 = f - rowi * 3;
        int al, j;
        if (TW) { al = rowi % 12; j = rowi / 12; }
        else    { al = rowi & 15; j = rowi >> 4; }
        int a = TW ? (al + 15) : (al ? al - 1 : 27);
        int q = (q3 == 0) ? q0 : ((q3 == 1) ? q1 : q2);
        int j2 = j << 1;
        float vv[4] = {vbuf[u].x, vbuf[u].y, vbuf[u].z, vbuf[u].w};
#pragma unroll
        for (int e = 0; e < 4; ++e) {
            int n = (q << 2) + e;
            int sl; bool ok;
            if (bc == 0) {
                if (n < 8)        { sl = n + 1;  ok = true; }
                else if (n >= 26) { sl = n - 17; ok = true; }
                else              { sl = 0;      ok = false; }
            } else {
                sl = n + 2 - c0;
                ok = (unsigned)sl < 10u;
            }
            if (ok) {
                int row  = a * 13 + sl;
                int byte = (row << 7) + (j2 ^ ((row & 7) << 4));
                *(unsigned short*)(smem + byte) = f2b(vv[e]);
            }
        }
    }
    __syncthreads();

    // ---- K-loop: NMT m-tiles x 2 n-tiles, 6 K-steps of 32 ----
    const int cl = rl & 7;
    const int rh = rl >> 3;
    int sidx[3];
#pragma unroll
    for (int k = 0; k < 3; ++k)
        sidx[k] = (bc == 0) ? ((cl == 0) ? (9 + k) : (cl - 1 + k)) : (cl + k);

    f32x4 acc[NMT][2];
#pragma unroll
    for (int mt = 0; mt < NMT; ++mt) {
        acc[mt][0] = f32x4{0.f, 0.f, 0.f, 0.f};
        acc[mt][1] = f32x4{0.f, 0.f, 0.f, 0.f};
    }

#pragma unroll
    for (int s = 0; s < 6; ++s) {
        const int k  = s >> 1;
        const int jb = ((s & 1) << 5) + jb0;
        const int jx = jb << 1;
        bf16x8 b0 = *reinterpret_cast<const bf16x8*>(wt + (k << 13) + (((w << 5) + rl) << 6) + jb);
        bf16x8 b1 = *reinterpret_cast<const bf16x8*>(wt + (k << 13) + (((w << 5) + 16 + rl) << 6) + jb);
#pragma unroll
        for (int mt = 0; mt < NMT; ++mt) {
            int al  = 2 * mt + rh;
            int a   = TW ? (al + 15) : (al ? al - 1 : 27);
            int row = a * 13 + sidx[k];
            int byte = (row << 7) + (jx ^ ((row & 7) << 4));
            bf16x8 af = *reinterpret_cast<const bf16x8*>(smem + byte);
            acc[mt][0] = __builtin_amdgcn_mfma_f32_16x16x32_bf16(af, b0, acc[mt][0], 0, 0, 0);
            acc[mt][1] = __builtin_amdgcn_mfma_f32_16x16x32_bf16(af, b1, acc[mt][1], 0, 0, 0);
        }
    }
    __syncthreads();

    // ---- epilogue write: t4s[ic][cl][ll], ll = rbase>>3 (roll pre-absorbed) ----
    {
        const int rq  = (lane >> 4) << 2;
        const int icb = (w << 5) + rl;
#pragma unroll
        for (int mt = 0; mt < NMT; ++mt) {
            int rbase = (mt << 4) + rq;
            int ll  = rbase >> 3;
            int clb = rbase & 7;                 // 0 or 4
            int l2  = ll << 1;
#pragma unroll
            for (int p = 0; p < 2; ++p) {
                int ic   = icb + (p << 4);
                int base = ic * 264 + l2;
#pragma unroll
                for (int q = 0; q < 4; ++q) {
                    *(unsigned short*)(smem + base + ((clb + q) << 5)) = f2b(acc[mt][p][q]);
                }
            }
        }
    }
    __syncthreads();

    // ---- combine with w0: 2 x ds_read_b64; nt stores of float4 ----
    constexpr int NLQ = TW ? 3 : 4;
    constexpr int TOT = 128 * 7 * NLQ;        // 2688 / 3584
    constexpr int CIT = (TOT + 255) >> 8;     // 11 / 14
#pragma unroll
    for (int u = 0; u < CIT; ++u) {
        int f = tid + (u << 8);
        if (TW && f >= TOT) continue;
        int lq, t1;
        if (TW) { t1 = f / 3; lq = f - 3 * t1; }
        else    { lq = f & 3; t1 = f >> 2; }
        int m_loc = t1 % 7;
        int iloc  = t1 / 7;
        float w00 = w0s[2 * iloc], w01 = w0s[2 * iloc + 1];
        int m    = c0 + m_loc;
        int base = iloc * 264 + (lq << 3);
        u16x4 h1 = *reinterpret_cast<const u16x4*>(smem + base + ((m_loc + 1) << 5));
        u16x4 h2 = *reinterpret_cast<const u16x4*>(smem + base + (m_loc << 5));
        f32x4 o;
        o.x = w00 * b2f(h1.x) + w01 * b2f(h2.x);
        o.y = w00 * b2f(h1.y) + w01 * b2f(h2.y);
        o.z = w00 * b2f(h1.z) + w01 * b2f(h2.z);
        o.w = w00 * b2f(h1.w) + w01 * b2f(h2.w);
        int lofs = (TW ? 16 : 0) + (lq << 2);
        __builtin_nontemporal_store(
            o, reinterpret_cast<f32x4*>(yb + iloc * 784 + m * 28 + lofs));
    }
}

__global__ __launch_bounds__(256, 3) void fused_main(
        const float* __restrict__ x, const float* __restrict__ w0,
        const unsigned short* __restrict__ wt, float* __restrict__ y) {
    __shared__ __align__(16) char smem[46592];
    __shared__ float w0s[256];

    const int tid = threadIdx.x;
    // dispatch: 8 consecutive blocks (4 bc x 2 twins) of one b per XCD -> L2 slab sharing
    const int B     = (int)blockIdx.x;
    const int xcd   = B & 7;
    const int g     = B >> 3;
    const int bc    = g & 3;
    const int tw    = (g >> 2) & 1;
    const int bslot = g >> 3;
    const int b     = (xcd << 7) + bslot;
    const int c0    = 7 * bc;

    w0s[tid] = w0[tid];

    const float* xb = x + (size_t)b * 50176;
    float* yb = y + (size_t)b * 100352;
    if (tw == 0) twin_body<0>(xb, yb, wt, w0s, smem, tid, bc, c0);
    else         twin_body<1>(xb, yb, wt, w0s, smem, tid, bc, c0);
}

extern "C" void kernel_launch(void* const* d_in, const int* in_sizes, int n_in,
                              void* d_out, int out_size, void* d_ws, size_t ws_size,
                              hipStream_t stream) {
    const float* x  = (const float*)d_in[0];
    const float* w0 = (const float*)d_in[1];
    const float* w1 = (const float*)d_in[2];
    float* y = (float*)d_out;
    unsigned short* wt = (unsigned short*)d_ws;   // 24576 u16 = 48 KiB

    hipLaunchKernelGGL(wt_prepass, dim3(96), dim3(256), 0, stream, w1, wt);
    hipLaunchKernelGGL(fused_main, dim3(8192), dim3(256), 0, stream, x, w0, wt, y);
}

// Round 13
// 172.278 us; speedup vs baseline: 1.8005x; 1.8005x over previous
//
#include <hip/hip_runtime.h>

typedef short bf16x8 __attribute__((ext_vector_type(8)));
typedef float f32x4 __attribute__((ext_vector_type(4)));
typedef unsigned short u16x4 __attribute__((ext_vector_type(4)));

__device__ __forceinline__ unsigned short f2b(float f) {
    unsigned int u = __builtin_bit_cast(unsigned int, f);
    u += 0x7fffu + ((u >> 16) & 1u);   // RNE
    return (unsigned short)(u >> 16);
}
__device__ __forceinline__ float b2f(unsigned short s) {
    unsigned int u = ((unsigned int)s) << 16;
    return __builtin_bit_cast(float, u);
}

// wt[k][i][j] = bf16(w1[j][k][i]);  k<3, i<128, j<64
__global__ void wt_prepass(const float* __restrict__ w1, unsigned short* __restrict__ wt) {
    int t = blockIdx.x * 256 + threadIdx.x;
    if (t >= 24576) return;
    int j = t & 63;
    int i = (t >> 6) & 127;
    int k = t >> 13;
    wt[t] = f2b(w1[(j * 3 + k) * 128 + i]);
}

// xs: row = a*13 + s; byte = (row<<7) + ((j*2) ^ ((row&7)<<4))   [46592 B]
// t4s (overlay): [ic][cl][l] u16, byte = ic*512 + cl*64 + ((l*2) ^ (((ic*7+cl)&7)<<3))
//   l = a+1 mod 28 applied at WRITE time; XOR scoped to l-dim -> injective.
// 512-thread block, one (b,bc) tile; waves 0-3: m-rows 0..111, waves 4-7: 112..223.

__global__ __launch_bounds__(512, 4) void fused_main(
        const float* __restrict__ x, const float* __restrict__ w0,
        const unsigned short* __restrict__ wt, float* __restrict__ y) {
    __shared__ __align__(16) char smem[65536];   // xs (46.6K) then t4s (64K)
    __shared__ float w0s[256];

    const int tid  = threadIdx.x;
    const int lane = tid & 63;
    const int w    = tid >> 6;          // 0..7
    const int rl   = lane & 15;
    const int jb0  = (lane >> 4) << 3;

    // same-XCD sibling mapping (bc-siblings of one b are 8 dispatch-slots apart)
    const int B   = (int)blockIdx.x;
    const int b   = ((B & 7) << 7) + ((B >> 3) >> 2);
    const int bc  = (B >> 3) & 3;
    const int c0  = 7 * bc;

    if (tid < 256) w0s[tid] = w0[tid];

    // ---- zero-fill halo slots (bc0: s=0,11 ; bc3: s=9) ----
    {
        int nh = (bc == 0) ? 2 : ((bc == 3) ? 1 : 0);
        for (int idx = tid; idx < nh * 224; idx += 512) {
            int rr = idx;
            int sl;
            if (bc == 0) {
                if (rr >= 224) { sl = 11; rr -= 224; } else sl = 0;
            } else {
                sl = 9;                 // bc == 3
            }
            int a   = rr >> 3, ch = rr & 7;
            int row = a * 13 + sl;
            int byte = (row << 7) + ((ch << 4) ^ ((row & 7) << 4));
            *reinterpret_cast<f32x4*>(smem + byte) = f32x4{0.f, 0.f, 0.f, 0.f};
        }
    }

    // ---- staging: 11 guarded batched float4 loads -> scatter ----
    int q0, q1, q2;
    if      (bc == 0) { q0 = 0; q1 = 1; q2 = 6; }
    else if (bc == 1) { q0 = 1; q1 = 2; q2 = 3; }
    else if (bc == 2) { q0 = 3; q1 = 4; q2 = 5; }
    else              { q0 = 4; q1 = 5; q2 = 6; }

    const float* xb = x + (size_t)b * (1792 * 28);
    {
        float4 vbuf[11];
#pragma unroll
        for (int u = 0; u < 11; ++u) {
            int f = tid + (u << 9);
            if (f < 5376) {
                int R  = f / 3;
                int q3 = f - R * 3;
                int q  = (q3 == 0) ? q0 : ((q3 == 1) ? q1 : q2);
                vbuf[u] = *reinterpret_cast<const float4*>(xb + R * 28 + (q << 2));
            }
        }
#pragma unroll
        for (int u = 0; u < 11; ++u) {
            int f = tid + (u << 9);
            if (f < 5376) {
                int R  = f / 3;
                int q3 = f - R * 3;
                int q  = (q3 == 0) ? q0 : ((q3 == 1) ? q1 : q2);
                int a  = R % 28;
                int j2 = (R / 28) << 1;
                float vv[4] = {vbuf[u].x, vbuf[u].y, vbuf[u].z, vbuf[u].w};
#pragma unroll
                for (int e = 0; e < 4; ++e) {
                    int n = (q << 2) + e;
                    int sl; bool ok;
                    if (bc == 0) {
                        if (n < 8)        { sl = n + 1;  ok = true; }
                        else if (n >= 26) { sl = n - 17; ok = true; }
                        else              { sl = 0;      ok = false; }
                    } else {
                        sl = n + 2 - c0;
                        ok = (unsigned)sl < 10u;
                    }
                    if (ok) {
                        int row  = a * 13 + sl;
                        int byte = (row << 7) + (j2 ^ ((row & 7) << 4));
                        *(unsigned short*)(smem + byte) = f2b(vv[e]);
                    }
                }
            }
        }
    }
    __syncthreads();

    // ---- K-loop: per wave 7 m-tiles x 2 n-tiles, 6 K-steps of 32 ----
    const int cl  = rl & 7;
    const int rh  = rl >> 3;
    const int mt0 = (w >> 2) * 7;       // wave-half m-tile base
    const int wn  = w & 3;              // n-group
    int rowoff[3];
#pragma unroll
    for (int k = 0; k < 3; ++k) {
        int sIdx = (bc == 0) ? ((cl == 0) ? (9 + k) : (cl - 1 + k)) : (cl + k);
        rowoff[k] = rh * 13 + sIdx;
    }

    f32x4 acc[7][2];
#pragma unroll
    for (int mt = 0; mt < 7; ++mt) {
        acc[mt][0] = f32x4{0.f, 0.f, 0.f, 0.f};
        acc[mt][1] = f32x4{0.f, 0.f, 0.f, 0.f};
    }

#pragma unroll
    for (int s = 0; s < 6; ++s) {
        const int k  = s >> 1;
        const int jb = ((s & 1) << 5) + jb0;
        const int jx = jb << 1;
        bf16x8 b0 = *reinterpret_cast<const bf16x8*>(wt + (k << 13) + (((wn << 5) + rl) << 6) + jb);
        bf16x8 b1 = *reinterpret_cast<const bf16x8*>(wt + (k << 13) + (((wn << 5) + 16 + rl) << 6) + jb);
#pragma unroll
        for (int mt = 0; mt < 7; ++mt) {
            int row  = 26 * (mt0 + mt) + rowoff[k];
            int byte = (row << 7) + (jx ^ ((row & 7) << 4));
            bf16x8 af = *reinterpret_cast<const bf16x8*>(smem + byte);
            acc[mt][0] = __builtin_amdgcn_mfma_f32_16x16x32_bf16(af, b0, acc[mt][0], 0, 0, 0);
            acc[mt][1] = __builtin_amdgcn_mfma_f32_16x16x32_bf16(af, b1, acc[mt][1], 0, 0, 0);
        }
    }
    __syncthreads();

    // ---- epilogue writes: t4s[ic][cl][l], scalar b16 ----
    {
        const int rq  = (lane >> 4) << 2;
        const int icb = (wn << 5) + rl;
#pragma unroll
        for (int mt = 0; mt < 7; ++mt) {
            int rbase = ((mt0 + mt) << 4) + rq;
            int a     = rbase >> 3;
            int l     = (a == 27) ? 0 : (a + 1);    // roll applied at write
            int l2    = l << 1;
            int clb   = rbase & 7;                  // 0 or 4
#pragma unroll
            for (int p = 0; p < 2; ++p) {
                int ic   = icb + (p << 4);
                int base = (ic << 9);
                int ic7  = ic * 7;
#pragma unroll
                for (int q = 0; q < 4; ++q) {
                    int cc   = clb + q;
                    int byte = base + (cc << 6) + (l2 ^ (((ic7 + cc) & 7) << 3));
                    *(unsigned short*)(smem + byte) = f2b(acc[mt][p][q]);
                }
            }
        }
    }
    __syncthreads();

    // ---- combine with w0: 2 x ds_read_b64 per output float4; nt stores ----
#pragma unroll
    for (int u = 0; u < 13; ++u) {
        int f = tid + (u << 9);
        if (f < 6272) {
            int lq    = f % 7;
            int t1    = f / 7;
            int m_loc = t1 % 7;
            int iloc  = t1 / 7;                     // 0..127
            float w00 = w0s[2 * iloc], w01 = w0s[2 * iloc + 1];
            int m     = c0 + m_loc;
            int lo    = lq << 3;
            int i7    = iloc * 7;
            int cl1   = m_loc + 1;                  // c = m
            int cl2   = m_loc;                      // c = m-1
            int by1   = (iloc << 9) + (cl1 << 6) + (lo ^ (((i7 + cl1) & 7) << 3));
            int by2   = (iloc << 9) + (cl2 << 6) + (lo ^ (((i7 + cl2) & 7) << 3));
            u16x4 h1  = *reinterpret_cast<const u16x4*>(smem + by1);
            u16x4 h2  = *reinterpret_cast<const u16x4*>(smem + by2);
            f32x4 o;
            o.x = w00 * b2f(h1.x) + w01 * b2f(h2.x);
            o.y = w00 * b2f(h1.y) + w01 * b2f(h2.y);
            o.z = w00 * b2f(h1.z) + w01 * b2f(h2.z);
            o.w = w00 * b2f(h1.w) + w01 * b2f(h2.w);
            __builtin_nontemporal_store(
                o, reinterpret_cast<f32x4*>(y + ((((size_t)b * 128 + iloc) * 28 + m) * 28) + (lq << 2)));
        }
    }
}

extern "C" void kernel_launch(void* const* d_in, const int* in_sizes, int n_in,
                              void* d_out, int out_size, void* d_ws, size_t ws_size,
                              hipStream_t stream) {
    const float* x  = (const float*)d_in[0];
    const float* w0 = (const float*)d_in[1];
    const float* w1 = (const float*)d_in[2];
    float* y = (float*)d_out;
    unsigned short* wt = (unsigned short*)d_ws;   // 24576 u16 = 48 KiB

    hipLaunchKernelGGL(wt_prepass, dim3(96), dim3(256), 0, stream, w1, wt);
    hipLaunchKernelGGL(fused_main, dim3(4096), dim3(512), 0, stream, x, w0, wt, y);
}